// Round 9
// baseline (38.930 us; speedup 1.0000x reference)
//
#include <hip/hip_runtime.h>
#include <hip/hip_fp16.h>

#define HOURS 24
#define RPB 256          // rows per block tile (= blockDim)
#define PSTR 25          // dwords per row in LDS: 24 half2 + 1 pad (gcd(25,32)=1)
#define SCOPE_AGENT __HIP_MEMORY_SCOPE_AGENT

// Workspace: float partials[6][nblocks]  (written via agent-scope atomic stores,
//            no init needed: every slot stored before the counter fires)
//            unsigned counter at byte offset 6*nblocks*4 rounded up to 128
//            (never reset; firing test uses modulo -> start-value independent)
// Slots: 0 sum(yp-yt)^2 all | 1 sum(yp-yt)^2 daytime | 2 sum(p_pv-t_pv)^2
//        3 sum(p_pt-t_pt)^2 | 4 sum mse_win (valid)  | 5 count valid

__global__ __launch_bounds__(256, 6) void peakloss_onekernel(
    const float* __restrict__ ypred, const float* __restrict__ ytrue,
    float* __restrict__ partials, unsigned* __restrict__ counter,
    float* __restrict__ out, int nrows, int nblocks,
    double inv_BS, double inv_BD) {
  __shared__ __half2 ltp[RPB * PSTR];   // 25.6 KB -> 6 blocks/CU

  const int tid = threadIdx.x;
  const int tile0 = blockIdx.x * RPB;
  const int rows = min(RPB, nrows - tile0);

  float s_sq = 0.f, s_day = 0.f, s_pv = 0.f, s_pt = 0.f, s_shape = 0.f, s_valid = 0.f;

  // ---- stage: coalesced float4 loads -> packed half2(t,p) LDS; fused fp32 MSE ----
  if (rows == RPB) {
    const float4* t4 = (const float4*)(ytrue + (size_t)tile0 * HOURS);
    const float4* p4 = (const float4*)(ypred + (size_t)tile0 * HOURS);
#pragma unroll
    for (int j = 0; j < 6; ++j) {
      int f4 = tid + j * 256;            // lane-contiguous float4 index
      float4 a = t4[f4];
      float4 b = p4[f4];
      int pa0 = f4 * 4 + f4 / 6;         // padded addr: d + d/24, d = 4*f4 (24%4==0)
      ltp[pa0 + 0] = __floats2half2_rn(a.x, b.x);
      ltp[pa0 + 1] = __floats2half2_rn(a.y, b.y);
      ltp[pa0 + 2] = __floats2half2_rn(a.z, b.z);
      ltp[pa0 + 3] = __floats2half2_rn(a.w, b.w);
      int h0 = 4 * (f4 % 6);             // hour of .x in {0,4,8,12,16,20}
      float dx = b.x - a.x, dy = b.y - a.y, dz = b.z - a.z, dw = b.w - a.w;
      float qx = dx * dx, qy = dy * dy, qz = dz * dz, qw = dw * dw;
      s_sq += qx + qy + qz + qw;
      s_day += ((h0 + 0 >= 6) & (h0 + 0 <= 20)) ? qx : 0.f;
      s_day += ((h0 + 1 >= 6) & (h0 + 1 <= 20)) ? qy : 0.f;
      s_day += ((h0 + 2 >= 6) & (h0 + 2 <= 20)) ? qz : 0.f;
      s_day += ((h0 + 3 >= 6) & (h0 + 3 <= 20)) ? qw : 0.f;
    }
  } else {
    for (int d = tid; d < rows * HOURS; d += 256) {
      float tv = ytrue[(size_t)tile0 * HOURS + d];
      float pv = ypred[(size_t)tile0 * HOURS + d];
      int pa = d + d / HOURS;
      ltp[pa] = __floats2half2_rn(tv, pv);
      float dd = (pv - tv) * (pv - tv);
      int h = d % HOURS;
      s_sq += dd;
      s_day += ((h >= 6) & (h <= 20)) ? dd : 0.f;
    }
  }
  __syncthreads();

  if (tid < rows) {
    const __half2* row = ltp + tid * PSTR;

    // pass A: daytime max/argmax (first-max semantics)
    float mt = -1e30f, mp = -1e30f;
    int idx = 6;
#pragma unroll
    for (int h = 6; h <= 20; ++h) {
      __half2 v = row[h];
      float th = __low2float(v), ph = __high2float(v);
      if (th > mt) { mt = th; idx = h; }
      mp = fmaxf(mp, ph);
    }

    // pass B: softmax sums (T=0.1) + windowed maxima & moment sums
    int ws = idx - 2;                    // [4,18]; window [ws,ws+5) within [4,23)
    float den_t = 0.f, nv_t = 0.f, nt_t = 0.f;
    float den_p = 0.f, nv_p = 0.f, nt_p = 0.f;
    float tmax = -1e30f, pmax = -1e30f;
    float St2 = 0.f, Sp2 = 0.f, Stp = 0.f;
#pragma unroll
    for (int h = 4; h <= 22; ++h) {
      __half2 v = row[h];
      float th = __low2float(v), ph = __high2float(v);
      if (h >= 6 && h <= 20) {
        float et = __expf((th - mt) * 10.f);
        den_t += et; nv_t += et * th; nt_t += et * (float)h;
        float ep = __expf((ph - mp) * 10.f);
        den_p += ep; nv_p += ep * ph; nt_p += ep * (float)h;
      }
      bool in = (h >= ws) & (h < ws + 5);
      if (in) {
        tmax = fmaxf(tmax, th); pmax = fmaxf(pmax, ph);
        St2 += th * th; Sp2 += ph * ph; Stp += th * ph;
      }
    }
    float r_t = __builtin_amdgcn_rcpf(den_t);
    float r_p = __builtin_amdgcn_rcpf(den_p);
    float dv  = nv_p * r_p - nv_t * r_t;
    float dtm = nt_p * r_p - nt_t * r_t;
    s_pv += dv * dv;
    s_pt += dtm * dtm;
    // sum_W (p*rp - t*rt)^2 = rp^2*Sp2 + rt^2*St2 - 2*rp*rt*Stp
    bool valid = tmax > 1e-6f;
    float tms = valid ? tmax : 1.0f;
    float rt = __builtin_amdgcn_rcpf(tms);
    float rp = __builtin_amdgcn_rcpf(pmax + 1e-6f);
    float aa = rp * rp * Sp2 + rt * rt * St2 - 2.f * rp * rt * Stp;
    if (valid) { s_shape += aa * 0.2f; s_valid += 1.0f; }
  }

  // ---- block reduction: wave shuffle -> LDS across 4 waves ----
  float v[6] = {s_sq, s_day, s_pv, s_pt, s_shape, s_valid};
#pragma unroll
  for (int j = 0; j < 6; ++j) {
#pragma unroll
    for (int off = 32; off >= 1; off >>= 1) v[j] += __shfl_down(v[j], off, 64);
  }
  __shared__ float red[6][4];
  int lane = threadIdx.x & 63, wave = threadIdx.x >> 6;
  __syncthreads();
  if (lane == 0) {
#pragma unroll
    for (int j = 0; j < 6; ++j) red[j][wave] = v[j];
  }
  __syncthreads();

  // ---- publish partials via agent-scope atomics; last-arriving block finalizes ----
  __shared__ int is_last;
  if (tid == 0) {
    float sums[6];
#pragma unroll
    for (int j = 0; j < 6; ++j) {
      sums[j] = red[j][0] + red[j][1] + red[j][2] + red[j][3];
      __hip_atomic_store(&partials[(size_t)j * nblocks + blockIdx.x], sums[j],
                         __ATOMIC_RELAXED, SCOPE_AGENT);
    }
    // completion wait (NOT a cache flush): partials are at the coherent point
    // before the counter bump below.
    asm volatile("s_waitcnt vmcnt(0)" ::: "memory");
    unsigned old = __hip_atomic_fetch_add(counter, 1u, __ATOMIC_RELAXED, SCOPE_AGENT);
    // modulo firing test: start-value independent (counter never reset, poison-immune)
    is_last = ((old % (unsigned)nblocks) == (unsigned)(nblocks - 1)) ? 1 : 0;
  }
  __syncthreads();
  if (!is_last) return;

  // firing block: all prior blocks' publishes are complete at the coherent point.
  double s[6] = {0, 0, 0, 0, 0, 0};
  for (int i = tid; i < nblocks; i += 256) {
#pragma unroll
    for (int j = 0; j < 6; ++j) {
      float pv = __hip_atomic_load(&partials[(size_t)j * nblocks + i],
                                   __ATOMIC_RELAXED, SCOPE_AGENT);
      s[j] += (double)pv;
    }
  }
#pragma unroll
  for (int j = 0; j < 6; ++j) {
#pragma unroll
    for (int off = 32; off >= 1; off >>= 1) s[j] += __shfl_down(s[j], off, 64);
  }
  __shared__ double dred[6][4];
  if (lane == 0) {
#pragma unroll
    for (int j = 0; j < 6; ++j) dred[j][wave] = s[j];
  }
  __syncthreads();
  if (tid == 0) {
    double a[6];
#pragma unroll
    for (int j = 0; j < 6; ++j)
      a[j] = dred[j][0] + dred[j][1] + dred[j][2] + dred[j][3];
    double L_overall = a[0] * inv_BS;
    double L_day     = a[1] * inv_BS;          // weighted_mse - L_overall
    double L_pv      = a[2] * inv_BD;
    double L_pt      = a[3] * inv_BD;
    double L_shape   = a[4] / (a[5] + 1e-6);
    out[0] = (float)(L_overall + 2.0 * L_pv + L_pt + 0.5 * L_shape + 0.5 * L_day);
  }
}

extern "C" void kernel_launch(void* const* d_in, const int* in_sizes, int n_in,
                              void* d_out, int out_size, void* d_ws, size_t ws_size,
                              hipStream_t stream) {
  const float* ypred = (const float*)d_in[0];
  const float* ytrue = (const float*)d_in[1];
  float* out = (float*)d_out;

  long long N = in_sizes[0];          // B * S
  int nrows = (int)(N / HOURS);       // B * D
  int grid = (nrows + RPB - 1) / RPB; // 1920 for the bench shape

  float* partials = (float*)d_ws;
  size_t coff = (((size_t)6 * grid * sizeof(float)) + 127ull) / 128ull * 128ull;
  unsigned* counter = (unsigned*)((char*)d_ws + coff);

  double inv_BS = 1.0 / (double)N;
  double inv_BD = 1.0 / (double)nrows;
  peakloss_onekernel<<<grid, 256, 0, stream>>>(ypred, ytrue, partials, counter,
                                               out, nrows, grid, inv_BS, inv_BD);
}

// Round 10
// 26.733 us; speedup vs baseline: 1.4562x; 1.4562x over previous
//
#include <hip/hip_runtime.h>

#define HOURS 24
#define RPB 256          // rows per block tile
#define PSTR 25          // padded dwords per row in LDS (gcd(25,32)=1 -> conflict-free)

// Workspace layout: float partials[6][num_blocks]
// 0: sum (yp-yt)^2 all | 1: sum (yp-yt)^2 daytime | 2: sum (p_pv-t_pv)^2
// 3: sum (p_pt-t_pt)^2 | 4: sum mse_win (valid)   | 5: count valid

__global__ __launch_bounds__(256) void peakloss_main(
    const float* __restrict__ ypred, const float* __restrict__ ytrue,
    float* __restrict__ partials, int nrows, int nblocks) {
  __shared__ float lt[RPB * PSTR];   // 25.6 KB
  __shared__ float lp[RPB * PSTR];   // 25.6 KB

  const int tid = threadIdx.x;
  const int tile0 = blockIdx.x * RPB;
  const int rows = min(RPB, nrows - tile0);

  // ---- stage: coalesced float4 global loads -> padded LDS (b32 scatter) ----
  if (rows == RPB) {
    const float4* t4 = (const float4*)(ytrue + (size_t)tile0 * HOURS);
    const float4* p4 = (const float4*)(ypred + (size_t)tile0 * HOURS);
#pragma unroll
    for (int j = 0; j < 6; ++j) {
      int f4 = tid + j * 256;            // 0..1535, lane-contiguous
      float4 a = t4[f4];
      float4 b = p4[f4];
      int d0 = f4 * 4;
      float av[4] = {a.x, a.y, a.z, a.w};
      float bv[4] = {b.x, b.y, b.z, b.w};
#pragma unroll
      for (int c = 0; c < 4; ++c) {
        int d = d0 + c;
        int pa = d + d / HOURS;          // insert 1 pad dword per 24
        lt[pa] = av[c];
        lp[pa] = bv[c];
      }
    }
  } else {
    for (int d = tid; d < rows * HOURS; d += 256) {
      int pa = d + d / HOURS;
      lt[pa] = ytrue[(size_t)tile0 * HOURS + d];
      lp[pa] = ypred[(size_t)tile0 * HOURS + d];
    }
  }
  __syncthreads();

  float s_sq = 0.f, s_day = 0.f, s_pv = 0.f, s_pt = 0.f, s_shape = 0.f, s_valid = 0.f;

  if (tid < rows) {
    const float* tr = lt + tid * PSTR;
    const float* pr = lp + tid * PSTR;

    // ---- pass 1: mse sums + daytime max/argmax (first-max semantics) ----
    float mt = -1e30f, mp = -1e30f;
    int idx = 6;
#pragma unroll
    for (int h = 0; h < HOURS; ++h) {
      float th = tr[h], ph = pr[h];
      float d = ph - th;
      float dd = d * d;
      s_sq += dd;
      if (h >= 6 && h <= 20) {
        s_day += dd;
        if (th > mt) { mt = th; idx = h; }
        mp = fmaxf(mp, ph);
      }
    }

    // ---- pass 2: softmax sums (T=0.1) + window maxima ----
    int ws = idx - 2;                    // in [4,18]; window [ws, ws+5) in [4,23)
    float den_t = 0.f, nv_t = 0.f, nt_t = 0.f;
    float den_p = 0.f, nv_p = 0.f, nt_p = 0.f;
    float tmax = -1e30f, pmax = -1e30f;
#pragma unroll
    for (int h = 4; h <= 22; ++h) {
      float th = tr[h], ph = pr[h];
      if (h >= 6 && h <= 20) {
        float et = __expf((th - mt) * 10.f);
        den_t += et; nv_t += et * th; nt_t += et * (float)h;
        float ep = __expf((ph - mp) * 10.f);
        den_p += ep; nv_p += ep * ph; nt_p += ep * (float)h;
      }
      bool in = (h >= ws) & (h < ws + 5);
      if (in) { tmax = fmaxf(tmax, th); pmax = fmaxf(pmax, ph); }
    }
    float r_t = __builtin_amdgcn_rcpf(den_t);
    float r_p = __builtin_amdgcn_rcpf(den_p);
    float dv  = nv_p * r_p - nv_t * r_t;
    float dtm = nt_p * r_p - nt_t * r_t;
    s_pv += dv * dv;
    s_pt += dtm * dtm;

    // ---- pass 3: windowed normalized shape mse ----
    bool valid = tmax > 1e-6f;
    float tms = valid ? tmax : 1.0f;
    float r_tms  = __builtin_amdgcn_rcpf(tms);
    float r_pden = __builtin_amdgcn_rcpf(pmax + 1e-6f);
    float a = 0.f;
#pragma unroll
    for (int h = 4; h <= 22; ++h) {
      bool in = (h >= ws) & (h < ws + 5);
      float d = pr[h] * r_pden - tr[h] * r_tms;
      a += in ? d * d : 0.f;
    }
    if (valid) { s_shape += a * 0.2f; s_valid += 1.0f; }
  }

  // ---- block reduction: wave shuffle -> LDS across 4 waves -> per-block write ----
  float v[6] = {s_sq, s_day, s_pv, s_pt, s_shape, s_valid};
#pragma unroll
  for (int j = 0; j < 6; ++j) {
#pragma unroll
    for (int off = 32; off >= 1; off >>= 1) v[j] += __shfl_down(v[j], off, 64);
  }
  __shared__ float red[6][4];
  int lane = threadIdx.x & 63, wave = threadIdx.x >> 6;
  __syncthreads();
  if (lane == 0) {
#pragma unroll
    for (int j = 0; j < 6; ++j) red[j][wave] = v[j];
  }
  __syncthreads();
  if (threadIdx.x < 6) {
    int j = threadIdx.x;
    partials[(size_t)j * nblocks + blockIdx.x] =
        red[j][0] + red[j][1] + red[j][2] + red[j][3];
  }
}

// Single-block final reduction in fp64; writes the scalar loss.
__global__ __launch_bounds__(256) void peakloss_reduce(
    const float* __restrict__ partials, float* __restrict__ out,
    int nblocks, double inv_BS, double inv_BD) {
  double s[6] = {0, 0, 0, 0, 0, 0};
  for (int i = threadIdx.x; i < nblocks; i += 256) {
#pragma unroll
    for (int j = 0; j < 6; ++j) s[j] += (double)partials[(size_t)j * nblocks + i];
  }
#pragma unroll
  for (int j = 0; j < 6; ++j) {
#pragma unroll
    for (int off = 32; off >= 1; off >>= 1) s[j] += __shfl_down(s[j], off, 64);
  }
  __shared__ double red[6][4];
  int lane = threadIdx.x & 63, wave = threadIdx.x >> 6;
  if (lane == 0) {
#pragma unroll
    for (int j = 0; j < 6; ++j) red[j][wave] = s[j];
  }
  __syncthreads();
  if (threadIdx.x == 0) {
    double a[6];
#pragma unroll
    for (int j = 0; j < 6; ++j)
      a[j] = red[j][0] + red[j][1] + red[j][2] + red[j][3];
    double L_overall = a[0] * inv_BS;
    double L_day     = a[1] * inv_BS;          // weighted_mse - L_overall
    double L_pv      = a[2] * inv_BD;
    double L_pt      = a[3] * inv_BD;
    double L_shape   = a[4] / (a[5] + 1e-6);
    out[0] = (float)(L_overall + 2.0 * L_pv + L_pt + 0.5 * L_shape + 0.5 * L_day);
  }
}

extern "C" void kernel_launch(void* const* d_in, const int* in_sizes, int n_in,
                              void* d_out, int out_size, void* d_ws, size_t ws_size,
                              hipStream_t stream) {
  const float* ypred = (const float*)d_in[0];
  const float* ytrue = (const float*)d_in[1];
  float* out = (float*)d_out;
  float* partials = (float*)d_ws;

  long long N = in_sizes[0];          // B * S
  int nrows = (int)(N / HOURS);       // B * D
  int grid = (nrows + RPB - 1) / RPB; // 1920 for the bench shape

  peakloss_main<<<grid, 256, 0, stream>>>(ypred, ytrue, partials, nrows, grid);

  double inv_BS = 1.0 / (double)N;
  double inv_BD = 1.0 / (double)nrows;
  peakloss_reduce<<<1, 256, 0, stream>>>(partials, out, grid, inv_BS, inv_BD);
}

// Round 11
// 26.322 us; speedup vs baseline: 1.4790x; 1.0156x over previous
//
#include <hip/hip_runtime.h>

#define HOURS 24

// Workspace: float partials[6][nblocks]
// 0 sum(yp-yt)^2 all | 1 sum(yp-yt)^2 daytime | 2 sum(p_pv-t_pv)^2
// 3 sum(p_pt-t_pt)^2 | 4 sum mse_win (valid)  | 5 count valid

__global__ __launch_bounds__(256) void peakloss_main(
    const float* __restrict__ ypred, const float* __restrict__ ytrue,
    float* __restrict__ partials, int nrows, int nblocks) {
  const int tid = threadIdx.x;
  const int r = blockIdx.x * 256 + tid;

  float s_sq = 0.f, s_day = 0.f, s_pv = 0.f, s_pt = 0.f, s_shape = 0.f, s_valid = 0.f;

  if (r < nrows) {
    // ---- direct load: 6+6 float4 per row into registers (all static indexing) ----
    float t[HOURS], p[HOURS];
    const float4* t4 = (const float4*)(ytrue + (size_t)r * HOURS);
    const float4* p4 = (const float4*)(ypred + (size_t)r * HOURS);
#pragma unroll
    for (int k = 0; k < 6; ++k) {
      float4 a = t4[k];
      t[4 * k + 0] = a.x; t[4 * k + 1] = a.y; t[4 * k + 2] = a.z; t[4 * k + 3] = a.w;
    }
#pragma unroll
    for (int k = 0; k < 6; ++k) {
      float4 b = p4[k];
      p[4 * k + 0] = b.x; p[4 * k + 1] = b.y; p[4 * k + 2] = b.z; p[4 * k + 3] = b.w;
    }

    // ---- pass 1: mse sums + daytime max/argmax (first-max semantics) ----
    float mt = -1e30f, mp = -1e30f;
    int idx = 6;
#pragma unroll
    for (int h = 0; h < HOURS; ++h) {
      float d = p[h] - t[h];
      float dd = d * d;
      s_sq += dd;
      if (h >= 6 && h <= 20) {
        s_day += dd;
        if (t[h] > mt) { mt = t[h]; idx = h; }
        mp = fmaxf(mp, p[h]);
      }
    }

    // ---- pass 2: softmax sums (T=0.1) + windowed maxima & moment sums ----
    int ws = idx - 2;                    // [4,18]; window [ws,ws+5) within [4,23)
    float den_t = 0.f, nv_t = 0.f, nt_t = 0.f;
    float den_p = 0.f, nv_p = 0.f, nt_p = 0.f;
    float tmax = -1e30f, pmax = -1e30f;
    float St2 = 0.f, Sp2 = 0.f, Stp = 0.f;
#pragma unroll
    for (int h = 4; h <= 22; ++h) {
      float th = t[h], ph = p[h];
      if (h >= 6 && h <= 20) {           // compile-time per unrolled iteration
        float et = __expf((th - mt) * 10.f);
        den_t += et; nv_t += et * th; nt_t += et * (float)h;
        float ep = __expf((ph - mp) * 10.f);
        den_p += ep; nv_p += ep * ph; nt_p += ep * (float)h;
      }
      bool in = (h >= ws) & (h < ws + 5);  // runtime ws only in compares, not indexing
      if (in) {
        tmax = fmaxf(tmax, th); pmax = fmaxf(pmax, ph);
        St2 += th * th; Sp2 += ph * ph; Stp += th * ph;
      }
    }
    float r_t = __builtin_amdgcn_rcpf(den_t);
    float r_p = __builtin_amdgcn_rcpf(den_p);
    float dv  = nv_p * r_p - nv_t * r_t;
    float dtm = nt_p * r_p - nt_t * r_t;
    s_pv += dv * dv;
    s_pt += dtm * dtm;

    // ---- pass 3 (algebraic): sum_W (p*rp - t*rt)^2 = rp^2*Sp2 + rt^2*St2 - 2*rp*rt*Stp
    bool valid = tmax > 1e-6f;
    float tms = valid ? tmax : 1.0f;
    float rt = __builtin_amdgcn_rcpf(tms);
    float rp = __builtin_amdgcn_rcpf(pmax + 1e-6f);
    float aa = rp * rp * Sp2 + rt * rt * St2 - 2.f * rp * rt * Stp;
    if (valid) { s_shape += aa * 0.2f; s_valid += 1.0f; }
  }

  // ---- block reduction: wave shuffle -> LDS across 4 waves -> per-block write ----
  float v[6] = {s_sq, s_day, s_pv, s_pt, s_shape, s_valid};
#pragma unroll
  for (int j = 0; j < 6; ++j) {
#pragma unroll
    for (int off = 32; off >= 1; off >>= 1) v[j] += __shfl_down(v[j], off, 64);
  }
  __shared__ float red[6][4];
  int lane = threadIdx.x & 63, wave = threadIdx.x >> 6;
  if (lane == 0) {
#pragma unroll
    for (int j = 0; j < 6; ++j) red[j][wave] = v[j];
  }
  __syncthreads();
  if (threadIdx.x < 6) {
    int j = threadIdx.x;
    partials[(size_t)j * nblocks + blockIdx.x] =
        red[j][0] + red[j][1] + red[j][2] + red[j][3];
  }
}

// Single-block final reduction in fp64; writes the scalar loss.
__global__ __launch_bounds__(256) void peakloss_reduce(
    const float* __restrict__ partials, float* __restrict__ out,
    int nblocks, double inv_BS, double inv_BD) {
  double s[6] = {0, 0, 0, 0, 0, 0};
  for (int i = threadIdx.x; i < nblocks; i += 256) {
#pragma unroll
    for (int j = 0; j < 6; ++j) s[j] += (double)partials[(size_t)j * nblocks + i];
  }
#pragma unroll
  for (int j = 0; j < 6; ++j) {
#pragma unroll
    for (int off = 32; off >= 1; off >>= 1) s[j] += __shfl_down(s[j], off, 64);
  }
  __shared__ double red[6][4];
  int lane = threadIdx.x & 63, wave = threadIdx.x >> 6;
  if (lane == 0) {
#pragma unroll
    for (int j = 0; j < 6; ++j) red[j][wave] = s[j];
  }
  __syncthreads();
  if (threadIdx.x == 0) {
    double a[6];
#pragma unroll
    for (int j = 0; j < 6; ++j)
      a[j] = red[j][0] + red[j][1] + red[j][2] + red[j][3];
    double L_overall = a[0] * inv_BS;
    double L_day     = a[1] * inv_BS;          // weighted_mse - L_overall
    double L_pv      = a[2] * inv_BD;
    double L_pt      = a[3] * inv_BD;
    double L_shape   = a[4] / (a[5] + 1e-6);
    out[0] = (float)(L_overall + 2.0 * L_pv + L_pt + 0.5 * L_shape + 0.5 * L_day);
  }
}

extern "C" void kernel_launch(void* const* d_in, const int* in_sizes, int n_in,
                              void* d_out, int out_size, void* d_ws, size_t ws_size,
                              hipStream_t stream) {
  const float* ypred = (const float*)d_in[0];
  const float* ytrue = (const float*)d_in[1];
  float* out = (float*)d_out;
  float* partials = (float*)d_ws;

  long long N = in_sizes[0];          // B * S
  int nrows = (int)(N / HOURS);       // B * D
  int grid = (nrows + 255) / 256;     // 1920 for the bench shape

  peakloss_main<<<grid, 256, 0, stream>>>(ypred, ytrue, partials, nrows, grid);

  double inv_BS = 1.0 / (double)N;
  double inv_BD = 1.0 / (double)nrows;
  peakloss_reduce<<<1, 256, 0, stream>>>(partials, out, grid, inv_BS, inv_BD);
}